// Round 1
// baseline (449.428 us; speedup 1.0000x reference)
//
#include <hip/hip_runtime.h>

// Problem constants
#define NVEC   65536      // B*R*C = 8*16*512
#define KDIM   64
#define SDIM   512
#define TILE_S 128
#define BLOCK  128

// Output layout (flat float32)
#define VH_OFF 0
#define Z_OFF  4194304          // NVEC*KDIM
#define LCOMMIT_OFF 4259840     // Z_OFF + NVEC
#define LCODE_OFF   4259841
#define E_OFF       4259842
// total = 4325378

// ws layout: c [SDIM*KDIM] floats, cnorm [SDIM] floats

__global__ void vq_prep(const float* __restrict__ c_sum,
                        const float* __restrict__ c_count,
                        float* __restrict__ c,
                        float* __restrict__ cnorm,
                        float* __restrict__ out) {
    int s = blockIdx.x;          // 0..511
    int k = threadIdx.x;         // 0..63
    float cnt = c_count[s];
    float inv = 1.0f / fmaxf(cnt, 0.01f);
    float val = c_sum[s * KDIM + k] * inv;
    c[s * KDIM + k] = val;
    float sq = val * val;
    // wave64 reduce
    #pragma unroll
    for (int off = 32; off > 0; off >>= 1)
        sq += __shfl_down(sq, off);
    if (k == 0) cnorm[s] = sq;
    if (s == 0 && k == 0) {
        out[LCOMMIT_OFF] = 0.0f;
        out[LCODE_OFF]   = 0.0f;
    }
}

__global__ __launch_bounds__(BLOCK) void vq_main(const float* __restrict__ vecs,
                                                 const float* __restrict__ cb,
                                                 const float* __restrict__ cnorm,
                                                 float* __restrict__ out) {
    __shared__ __align__(16) float cLds[TILE_S * KDIM];  // 32 KB
    __shared__ float cnLds[TILE_S];

    const int vid = blockIdx.x * BLOCK + threadIdx.x;    // 0..65535

    // load this thread's vector into registers (64 floats = 16 float4)
    const float4* v4 = (const float4*)(vecs + (size_t)vid * KDIM);
    float4 v[16];
    #pragma unroll
    for (int i = 0; i < 16; ++i) v[i] = v4[i];

    float vnorm = 0.0f;
    #pragma unroll
    for (int i = 0; i < 16; ++i)
        vnorm += v[i].x * v[i].x + v[i].y * v[i].y + v[i].z * v[i].z + v[i].w * v[i].w;

    float best = 3.4e38f;
    int bidx = 0;

    for (int t = 0; t < SDIM / TILE_S; ++t) {
        __syncthreads();  // protect previous tile from being overwritten while in use
        // stage tile: TILE_S*KDIM floats = 2048 float4, 128 threads -> 16 each
        const float4* src = (const float4*)(cb + (size_t)t * TILE_S * KDIM);
        float4* dst = (float4*)cLds;
        #pragma unroll
        for (int i = 0; i < (TILE_S * KDIM / 4) / BLOCK; ++i)
            dst[threadIdx.x + i * BLOCK] = src[threadIdx.x + i * BLOCK];
        if (threadIdx.x < TILE_S)
            cnLds[threadIdx.x] = cnorm[t * TILE_S + threadIdx.x];
        __syncthreads();

        #pragma unroll 2
        for (int s = 0; s < TILE_S; ++s) {
            const float4* cr = (const float4*)(cLds + s * KDIM);
            float d0 = 0.f, d1 = 0.f, d2 = 0.f, d3 = 0.f;
            #pragma unroll
            for (int i = 0; i < 16; ++i) {
                float4 cv = cr[i];
                d0 = fmaf(v[i].x, cv.x, d0);
                d1 = fmaf(v[i].y, cv.y, d1);
                d2 = fmaf(v[i].z, cv.z, d2);
                d3 = fmaf(v[i].w, cv.w, d3);
            }
            float dot = (d0 + d1) + (d2 + d3);
            float dist = vnorm - 2.0f * dot + cnLds[s];
            int sg = t * TILE_S + s;
            if (dist < best) { best = dist; bidx = sg; }   // strict <: first-index tie-break
        }
    }

    float err = fmaxf(best, 0.0f);
    out[Z_OFF + vid] = (float)bidx;   // z as float (flat f32 output buffer)
    out[E_OFF + vid] = err;

    // gather codeword -> vecs_hat (forward value of sg(cz)+st(vecs) is cz)
    const float4* crow = (const float4*)(cb + (size_t)bidx * KDIM);
    float4* o4 = (float4*)(out + (size_t)vid * KDIM);
    #pragma unroll
    for (int i = 0; i < 16; ++i) o4[i] = crow[i];

    // l_commit = mean(errs2): wave-reduce then one atomic per wave (scaled)
    float esum = err;
    #pragma unroll
    for (int off = 32; off > 0; off >>= 1)
        esum += __shfl_down(esum, off);
    if ((threadIdx.x & 63) == 0)
        atomicAdd(out + LCOMMIT_OFF, esum * (1.0f / (float)NVEC));
}

extern "C" void kernel_launch(void* const* d_in, const int* in_sizes, int n_in,
                              void* d_out, int out_size, void* d_ws, size_t ws_size,
                              hipStream_t stream) {
    const float* vecs    = (const float*)d_in[0];  // [8,16,512,64]
    const float* c_sum   = (const float*)d_in[1];  // [512,64]
    const float* c_count = (const float*)d_in[2];  // [512]
    float* out = (float*)d_out;

    float* c     = (float*)d_ws;                   // 512*64 floats
    float* cnorm = c + SDIM * KDIM;                // 512 floats

    vq_prep<<<SDIM, KDIM, 0, stream>>>(c_sum, c_count, c, cnorm, out);
    vq_main<<<NVEC / BLOCK, BLOCK, 0, stream>>>(vecs, c, cnorm, out);
}

// Round 2
// 386.923 us; speedup vs baseline: 1.1615x; 1.1615x over previous
//
#include <hip/hip_runtime.h>

// Problem constants
#define NVEC   65536      // B*R*C = 8*16*512
#define KDIM   64
#define SDIM   512
#define TS     128        // codewords per LDS tile
#define NT     (SDIM/TS)  // 4 tiles
#define VR     8          // vectors per wave
#define BLOCK  256        // 4 waves

// Output layout (flat float32)
#define Z_OFF       4194304     // NVEC*KDIM
#define LCOMMIT_OFF 4259840
#define LCODE_OFF   4259841
#define E_OFF       4259842

// ws layout: c [SDIM*KDIM], cnorm [SDIM], vnorm [NVEC]

__global__ void vq_prep(const float* __restrict__ c_sum,
                        const float* __restrict__ c_count,
                        float* __restrict__ c,
                        float* __restrict__ cnorm,
                        float* __restrict__ out) {
    int s = blockIdx.x;          // 0..511
    int k = threadIdx.x;         // 0..63
    float cnt = c_count[s];
    float inv = 1.0f / fmaxf(cnt, 0.01f);
    float val = c_sum[s * KDIM + k] * inv;
    c[s * KDIM + k] = val;
    float sq = val * val;
    #pragma unroll
    for (int off = 32; off > 0; off >>= 1)
        sq += __shfl_down(sq, off);
    if (k == 0) cnorm[s] = sq;
    if (s == 0 && k == 0) {
        out[LCOMMIT_OFF] = 0.0f;
        out[LCODE_OFF]   = 0.0f;
    }
}

// vnorm with the EXACT round-1 expression tree (bit-compat with the passing kernel)
__global__ void vq_vnorm(const float* __restrict__ vecs, float* __restrict__ vnorm) {
    int vid = blockIdx.x * 256 + threadIdx.x;
    const float4* v4 = (const float4*)(vecs + (size_t)vid * KDIM);
    float4 v[16];
    #pragma unroll
    for (int i = 0; i < 16; ++i) v[i] = v4[i];
    float vn = 0.0f;
    #pragma unroll
    for (int i = 0; i < 16; ++i)
        vn += v[i].x * v[i].x + v[i].y * v[i].y + v[i].z * v[i].z + v[i].w * v[i].w;
    vnorm[vid] = vn;
}

__global__ __launch_bounds__(BLOCK, 4) void vq_main(const float* __restrict__ vecs,
                                                    const float* __restrict__ cb,
                                                    const float* __restrict__ cnorm,
                                                    const float* __restrict__ vnorm,
                                                    float* __restrict__ out) {
    // cw layout: [c][s][j]  (c = k-chunk 0..15, s = 0..127, j = 0..3) -> float4 index c*TS+s
    __shared__ __align__(16) float cw[TS * KDIM];   // 32 KB
    __shared__ float cn[TS];

    const int lane = threadIdx.x & 63;
    // force wave-uniformity so vector loads scalarize to s_load (SMEM pipe)
    const int wave = __builtin_amdgcn_readfirstlane(threadIdx.x >> 6);
    const int wvec = __builtin_amdgcn_readfirstlane((int)blockIdx.x * ((BLOCK / 64) * VR) + wave * VR);
    const float* __restrict__ va = vecs + (size_t)wvec * KDIM;

    float vn[VR];
    #pragma unroll
    for (int v = 0; v < VR; ++v) vn[v] = vnorm[wvec + v];   // uniform -> SGPR

    float best[VR];
    int   bidx[VR];
    #pragma unroll
    for (int v = 0; v < VR; ++v) { best[v] = 3.4e38f; bidx[v] = 0; }

    for (int t = 0; t < NT; ++t) {
        __syncthreads();
        // stage tile: TS*KDIM floats = 2048 float4, 256 threads -> 8 each
        const float4* src = (const float4*)(cb + (size_t)t * TS * KDIM);
        float4* dst = (float4*)cw;
        #pragma unroll
        for (int i = 0; i < (TS * KDIM / 4) / BLOCK; ++i) {
            int idx = i * BLOCK + threadIdx.x;
            int s   = idx & (TS - 1);
            int c   = idx >> 7;
            dst[c * TS + s] = src[s * (KDIM / 4) + c];
        }
        if (threadIdx.x < TS) cn[threadIdx.x] = cnorm[t * TS + threadIdx.x];
        __syncthreads();

        // accumulators: 8 vec x 2 cw x 4 chains (chain = k%4, EXACT round-1 tree)
        float d[VR][2][4];
        #pragma unroll
        for (int v = 0; v < VR; ++v)
            #pragma unroll
            for (int p = 0; p < 2; ++p)
                #pragma unroll
                for (int j = 0; j < 4; ++j) d[v][p][j] = 0.0f;

        const float4* b4 = (const float4*)cw;
        #pragma unroll
        for (int c = 0; c < KDIM / 4; ++c) {
            float4 bv0 = b4[c * TS + lane];        // codeword s = t*TS + lane
            float4 bv1 = b4[c * TS + 64 + lane];   // codeword s = t*TS + 64 + lane
            float4 av[VR];
            #pragma unroll
            for (int v = 0; v < VR; ++v)
                av[v] = ((const float4*)(va + (size_t)v * KDIM))[c];  // uniform -> s_load
            #pragma unroll
            for (int v = 0; v < VR; ++v) {
                d[v][0][0] = fmaf(av[v].x, bv0.x, d[v][0][0]);
                d[v][0][1] = fmaf(av[v].y, bv0.y, d[v][0][1]);
                d[v][0][2] = fmaf(av[v].z, bv0.z, d[v][0][2]);
                d[v][0][3] = fmaf(av[v].w, bv0.w, d[v][0][3]);
                d[v][1][0] = fmaf(av[v].x, bv1.x, d[v][1][0]);
                d[v][1][1] = fmaf(av[v].y, bv1.y, d[v][1][1]);
                d[v][1][2] = fmaf(av[v].z, bv1.z, d[v][1][2]);
                d[v][1][3] = fmaf(av[v].w, bv1.w, d[v][1][3]);
            }
        }

        // epilogue: dist + running argmin (strict <, increasing s => first-occurrence)
        #pragma unroll
        for (int v = 0; v < VR; ++v) {
            float dot0  = (d[v][0][0] + d[v][0][1]) + (d[v][0][2] + d[v][0][3]);
            float dist0 = vn[v] - 2.0f * dot0 + cn[lane];
            int   s0    = t * TS + lane;
            if (dist0 < best[v]) { best[v] = dist0; bidx[v] = s0; }
            float dot1  = (d[v][1][0] + d[v][1][1]) + (d[v][1][2] + d[v][1][3]);
            float dist1 = vn[v] - 2.0f * dot1 + cn[64 + lane];
            int   s1    = t * TS + 64 + lane;
            if (dist1 < best[v]) { best[v] = dist1; bidx[v] = s1; }
        }
    }

    // cross-lane argmin reduce per vector: (val, then idx) -> first-occurrence semantics
    float esum = 0.0f;
    #pragma unroll
    for (int v = 0; v < VR; ++v) {
        float bv = best[v];
        int   bi = bidx[v];
        #pragma unroll
        for (int off = 32; off > 0; off >>= 1) {
            float ov = __shfl_xor(bv, off);
            int   oi = __shfl_xor(bi, off);
            if (ov < bv || (ov == bv && oi < bi)) { bv = ov; bi = oi; }
        }
        // all lanes now hold the final (bv, bi)
        out[(size_t)(wvec + v) * KDIM + lane] = cb[(size_t)bi * KDIM + lane];  // vecs_hat
        if (lane == 0) {
            out[Z_OFF + wvec + v] = (float)bi;
            out[E_OFF + wvec + v] = fmaxf(bv, 0.0f);
        }
        esum += fmaxf(bv, 0.0f);
    }
    if (lane == 0)
        atomicAdd(out + LCOMMIT_OFF, esum * (1.0f / (float)NVEC));
}

extern "C" void kernel_launch(void* const* d_in, const int* in_sizes, int n_in,
                              void* d_out, int out_size, void* d_ws, size_t ws_size,
                              hipStream_t stream) {
    const float* vecs    = (const float*)d_in[0];  // [8,16,512,64]
    const float* c_sum   = (const float*)d_in[1];  // [512,64]
    const float* c_count = (const float*)d_in[2];  // [512]
    float* out = (float*)d_out;

    float* c     = (float*)d_ws;                   // 512*64
    float* cnorm = c + SDIM * KDIM;                // 512
    float* vnorm = cnorm + SDIM;                   // 65536

    vq_prep<<<SDIM, KDIM, 0, stream>>>(c_sum, c_count, c, cnorm, out);
    vq_vnorm<<<NVEC / 256, 256, 0, stream>>>(vecs, vnorm);
    vq_main<<<NVEC / (VR * (BLOCK / 64)), BLOCK, 0, stream>>>(vecs, c, cnorm, vnorm, out);
}

// Round 3
// 257.218 us; speedup vs baseline: 1.7473x; 1.5043x over previous
//
#include <hip/hip_runtime.h>

// Problem constants
#define NVEC   65536      // B*R*C = 8*16*512
#define KDIM   64
#define SDIM   512
#define TS     128        // codewords per LDS tile
#define NT     (SDIM/TS)  // 4 tiles
#define VR     8          // vectors per wave
#define BLOCK  256        // 4 waves

// Output layout (flat float32)
#define Z_OFF       4194304     // NVEC*KDIM
#define LCOMMIT_OFF 4259840
#define LCODE_OFF   4259841
#define E_OFF       4259842

// ws layout: c [SDIM*KDIM], cnorm [SDIM], vnorm [NVEC]

__global__ void vq_prep(const float* __restrict__ c_sum,
                        const float* __restrict__ c_count,
                        float* __restrict__ c,
                        float* __restrict__ cnorm,
                        float* __restrict__ out) {
    int s = blockIdx.x;          // 0..511
    int k = threadIdx.x;         // 0..63
    float cnt = c_count[s];
    float inv = 1.0f / fmaxf(cnt, 0.01f);
    float val = c_sum[s * KDIM + k] * inv;
    c[s * KDIM + k] = val;
    float sq = val * val;
    #pragma unroll
    for (int off = 32; off > 0; off >>= 1)
        sq += __shfl_down(sq, off);
    if (k == 0) cnorm[s] = sq;
    if (s == 0 && k == 0) {
        out[LCOMMIT_OFF] = 0.0f;
        out[LCODE_OFF]   = 0.0f;
    }
}

// vnorm with the EXACT round-1 expression tree (bit-compat with the passing kernel)
__global__ void vq_vnorm(const float* __restrict__ vecs, float* __restrict__ vnorm) {
    int vid = blockIdx.x * 256 + threadIdx.x;
    const float4* v4 = (const float4*)(vecs + (size_t)vid * KDIM);
    float4 v[16];
    #pragma unroll
    for (int i = 0; i < 16; ++i) v[i] = v4[i];
    float vn = 0.0f;
    #pragma unroll
    for (int i = 0; i < 16; ++i)
        vn += v[i].x * v[i].x + v[i].y * v[i].y + v[i].z * v[i].z + v[i].w * v[i].w;
    vnorm[vid] = vn;
}

// launch_bounds(256, 2): 256-VGPR budget. R2's (256,4) capped VGPRs at 64 and
// the 64-acc register tile spilled to scratch -> 870 MB phantom HBM traffic.
__global__ __launch_bounds__(BLOCK, 2) void vq_main(const float* __restrict__ vecs,
                                                    const float* __restrict__ cb,
                                                    const float* __restrict__ cnorm,
                                                    const float* __restrict__ vnorm,
                                                    float* __restrict__ out) {
    // cw layout: [c][s][j]  (c = k-chunk 0..15, s = 0..127, j = 0..3) -> float4 index c*TS+s
    __shared__ __align__(16) float cw[TS * KDIM];   // 32 KB
    __shared__ float cn[TS];

    const int lane = threadIdx.x & 63;
    // force wave-uniformity so vector loads scalarize to s_load (SMEM pipe)
    const int wave = __builtin_amdgcn_readfirstlane(threadIdx.x >> 6);
    const int wvec = __builtin_amdgcn_readfirstlane((int)blockIdx.x * ((BLOCK / 64) * VR) + wave * VR);
    const float* __restrict__ va = vecs + (size_t)wvec * KDIM;

    float vn[VR];
    #pragma unroll
    for (int v = 0; v < VR; ++v) vn[v] = vnorm[wvec + v];   // uniform -> SGPR

    float best[VR];
    int   bidx[VR];
    #pragma unroll
    for (int v = 0; v < VR; ++v) { best[v] = 3.4e38f; bidx[v] = 0; }

    for (int t = 0; t < NT; ++t) {
        __syncthreads();
        // stage tile: TS*KDIM floats = 2048 float4, 256 threads -> 8 each
        const float4* src = (const float4*)(cb + (size_t)t * TS * KDIM);
        float4* dst = (float4*)cw;
        #pragma unroll
        for (int i = 0; i < (TS * KDIM / 4) / BLOCK; ++i) {
            int idx = i * BLOCK + threadIdx.x;
            int s   = idx & (TS - 1);
            int c   = idx >> 7;
            dst[c * TS + s] = src[s * (KDIM / 4) + c];
        }
        if (threadIdx.x < TS) cn[threadIdx.x] = cnorm[t * TS + threadIdx.x];
        __syncthreads();

        // accumulators: 8 vec x 2 cw x 4 chains (chain = k%4, EXACT round-1 tree)
        float d[VR][2][4];
        #pragma unroll
        for (int v = 0; v < VR; ++v)
            #pragma unroll
            for (int p = 0; p < 2; ++p)
                #pragma unroll
                for (int j = 0; j < 4; ++j) d[v][p][j] = 0.0f;

        const float4* b4 = (const float4*)cw;
        #pragma unroll
        for (int c = 0; c < KDIM / 4; ++c) {
            float4 bv0 = b4[c * TS + lane];        // codeword s = t*TS + lane
            float4 bv1 = b4[c * TS + 64 + lane];   // codeword s = t*TS + 64 + lane
            float4 av[VR];
            #pragma unroll
            for (int v = 0; v < VR; ++v)
                av[v] = ((const float4*)(va + (size_t)v * KDIM))[c];  // uniform -> s_load
            #pragma unroll
            for (int v = 0; v < VR; ++v) {
                d[v][0][0] = fmaf(av[v].x, bv0.x, d[v][0][0]);
                d[v][0][1] = fmaf(av[v].y, bv0.y, d[v][0][1]);
                d[v][0][2] = fmaf(av[v].z, bv0.z, d[v][0][2]);
                d[v][0][3] = fmaf(av[v].w, bv0.w, d[v][0][3]);
                d[v][1][0] = fmaf(av[v].x, bv1.x, d[v][1][0]);
                d[v][1][1] = fmaf(av[v].y, bv1.y, d[v][1][1]);
                d[v][1][2] = fmaf(av[v].z, bv1.z, d[v][1][2]);
                d[v][1][3] = fmaf(av[v].w, bv1.w, d[v][1][3]);
            }
        }

        // epilogue: dist + running argmin (strict <, increasing s => first-occurrence)
        #pragma unroll
        for (int v = 0; v < VR; ++v) {
            float dot0  = (d[v][0][0] + d[v][0][1]) + (d[v][0][2] + d[v][0][3]);
            float dist0 = vn[v] - 2.0f * dot0 + cn[lane];
            int   s0    = t * TS + lane;
            if (dist0 < best[v]) { best[v] = dist0; bidx[v] = s0; }
            float dot1  = (d[v][1][0] + d[v][1][1]) + (d[v][1][2] + d[v][1][3]);
            float dist1 = vn[v] - 2.0f * dot1 + cn[64 + lane];
            int   s1    = t * TS + 64 + lane;
            if (dist1 < best[v]) { best[v] = dist1; bidx[v] = s1; }
        }
    }

    // cross-lane argmin reduce per vector: (val, then idx) -> first-occurrence semantics
    float esum = 0.0f;
    #pragma unroll
    for (int v = 0; v < VR; ++v) {
        float bv = best[v];
        int   bi = bidx[v];
        #pragma unroll
        for (int off = 32; off > 0; off >>= 1) {
            float ov = __shfl_xor(bv, off);
            int   oi = __shfl_xor(bi, off);
            if (ov < bv || (ov == bv && oi < bi)) { bv = ov; bi = oi; }
        }
        // all lanes now hold the final (bv, bi)
        out[(size_t)(wvec + v) * KDIM + lane] = cb[(size_t)bi * KDIM + lane];  // vecs_hat
        if (lane == 0) {
            out[Z_OFF + wvec + v] = (float)bi;
            out[E_OFF + wvec + v] = fmaxf(bv, 0.0f);
        }
        esum += fmaxf(bv, 0.0f);
    }
    if (lane == 0)
        atomicAdd(out + LCOMMIT_OFF, esum * (1.0f / (float)NVEC));
}

extern "C" void kernel_launch(void* const* d_in, const int* in_sizes, int n_in,
                              void* d_out, int out_size, void* d_ws, size_t ws_size,
                              hipStream_t stream) {
    const float* vecs    = (const float*)d_in[0];  // [8,16,512,64]
    const float* c_sum   = (const float*)d_in[1];  // [512,64]
    const float* c_count = (const float*)d_in[2];  // [512]
    float* out = (float*)d_out;

    float* c     = (float*)d_ws;                   // 512*64
    float* cnorm = c + SDIM * KDIM;                // 512
    float* vnorm = cnorm + SDIM;                   // 65536

    vq_prep<<<SDIM, KDIM, 0, stream>>>(c_sum, c_count, c, cnorm, out);
    vq_vnorm<<<NVEC / 256, 256, 0, stream>>>(vecs, vnorm);
    vq_main<<<NVEC / (VR * (BLOCK / 64)), BLOCK, 0, stream>>>(vecs, c, cnorm, vnorm, out);
}

// Round 4
// 120.013 us; speedup vs baseline: 3.7448x; 2.1433x over previous
//
#include <hip/hip_runtime.h>

// Problem constants
#define NVEC   65536      // B*R*C = 8*16*512
#define KDIM   64
#define SDIM   512

// Output layout (flat float32)
#define Z_OFF       4194304     // NVEC*KDIM
#define LCOMMIT_OFF 4259840
#define LCODE_OFF   4259841
#define E_OFF       4259842

typedef _Float16 half8   __attribute__((ext_vector_type(8)));
typedef float    floatx16 __attribute__((ext_vector_type(16)));

// ws layout: c32 [SDIM*KDIM] f32, cnorm [SDIM] f32, cbf16 [SDIM*KDIM*2] f16
//
// cbf16 chunk layout (16-B chunks of 8 f16):
//   chunk((g,sub?)=s>>5, c=p*8+q*2+h, n=s&31) at linear ((s>>5)*16 + c)*32 + n
//   holding f16 prec-p of codeword s, k = q*16 + h*8 .. +7.
// In the main kernel this collapses to pure lane-linear reads:
//   addr(lane) = sub*4096 + (p*8+q*2)*256 + lane*8   (halfs)

__global__ void vq_prep(const float* __restrict__ c_sum,
                        const float* __restrict__ c_count,
                        float* __restrict__ c32,
                        float* __restrict__ cnorm,
                        _Float16* __restrict__ cbf16,
                        float* __restrict__ out) {
    int s = blockIdx.x;          // 0..511
    int k = threadIdx.x;         // 0..63
    float cnt = c_count[s];
    float inv = 1.0f / fmaxf(cnt, 0.01f);
    float x = c_sum[s * KDIM + k] * inv;
    c32[s * KDIM + k] = x;
    float sq = x * x;
    #pragma unroll
    for (int off = 32; off > 0; off >>= 1)
        sq += __shfl_down(sq, off);
    if (k == 0) cnorm[s] = sq;

    __shared__ _Float16 hb[64], lb[64];
    _Float16 hi = (_Float16)x;
    float hiF = (float)hi;
    _Float16 lo = (_Float16)(x - hiF);
    hb[k] = hi; lb[k] = lo;
    __syncthreads();
    if (k < 16) {
        int p  = k >> 3;
        int qh = k & 7;                       // q*2 + h
        int k0 = (qh >> 1) * 16 + (qh & 1) * 8;
        const _Float16* srcb = (p ? lb : hb) + k0;
        half8 v;
        #pragma unroll
        for (int j = 0; j < 8; ++j) v[j] = srcb[j];
        size_t chunk = ((size_t)(s >> 5) * 16 + p * 8 + qh) * 32 + (s & 31);
        *(half8*)(cbf16 + chunk * 8) = v;
    }
    if (s == 0 && k == 0) {
        out[LCOMMIT_OFF] = 0.0f;
        out[LCODE_OFF]   = 0.0f;
    }
}

// block = 128 threads = 2 waves; each wave owns 32 vectors (M=32), streams all
// 512 codewords through 4x 32KB LDS tiles using v_mfma_f32_32x32x16_f16.
__global__ __launch_bounds__(128, 2) void vq_main(const float* __restrict__ vecs,
                                                  const _Float16* __restrict__ cbf16,
                                                  const float* __restrict__ c32,
                                                  const float* __restrict__ cnorm,
                                                  float* __restrict__ out) {
    __shared__ __align__(16) _Float16 cw[16384];   // 32 KB B-tile (128 cw)
    __shared__ float cnL[128];
    __shared__ float vnL[2][32];
    __shared__ int   zL[2][32];

    const int tx   = threadIdx.x;
    const int lane = tx & 63;
    const int w    = tx >> 6;
    const int col  = lane & 31;
    const int h    = lane >> 5;
    const int wvec = (int)blockIdx.x * 64 + w * 32;

    // ---- A fragments (hi/lo f16) + vnorm partial ----
    half8 ahi[4], alo[4];
    float vnp = 0.0f;
    const float* arow = vecs + (size_t)(wvec + col) * KDIM + h * 8;
    #pragma unroll
    for (int q = 0; q < 4; ++q) {
        float4 x0 = *(const float4*)(arow + q * 16);
        float4 x1 = *(const float4*)(arow + q * 16 + 4);
        #define CVT(X, J) { float xx = (X); _Float16 hi5 = (_Float16)xx; \
                            float hf = (float)hi5; ahi[q][J] = hi5; \
                            alo[q][J] = (_Float16)(xx - hf); vnp += xx * xx; }
        CVT(x0.x, 0) CVT(x0.y, 1) CVT(x0.z, 2) CVT(x0.w, 3)
        CVT(x1.x, 4) CVT(x1.y, 5) CVT(x1.z, 6) CVT(x1.w, 7)
        #undef CVT
    }
    vnp += __shfl_xor(vnp, 32);
    if (h == 0) vnL[w][col] = vnp;

    float bq[16];
    int   bi[16];
    #pragma unroll
    for (int r = 0; r < 16; ++r) { bq[r] = 3.4e38f; bi[r] = 0; }

    for (int t = 0; t < 4; ++t) {
        __syncthreads();
        const float4* src = (const float4*)(cbf16 + (size_t)t * 16384);
        float4* dst = (float4*)cw;
        #pragma unroll 4
        for (int i = 0; i < 16; ++i)
            dst[i * 128 + tx] = src[i * 128 + tx];
        if (tx < 128) cnL[tx] = cnorm[t * 128 + tx];
        __syncthreads();

        #pragma unroll
        for (int sub = 0; sub < 4; ++sub) {
            const _Float16* bb = cw + sub * 4096 + lane * 8;
            floatx16 a0 = {0.0f}, a1 = {0.0f}, a2 = {0.0f};
            #pragma unroll
            for (int q = 0; q < 4; ++q) {
                half8 bh = *(const half8*)(bb + q * 512);           // prec hi
                half8 bl = *(const half8*)(bb + 2048 + q * 512);    // prec lo
                a0 = __builtin_amdgcn_mfma_f32_32x32x16_f16(ahi[q], bh, a0, 0, 0, 0);
                a1 = __builtin_amdgcn_mfma_f32_32x32x16_f16(alo[q], bh, a1, 0, 0, 0);
                a2 = __builtin_amdgcn_mfma_f32_32x32x16_f16(ahi[q], bl, a2, 0, 0, 0);
            }
            float cnv = cnL[sub * 32 + col];
            int   n   = t * 128 + sub * 32 + col;
            #pragma unroll
            for (int r = 0; r < 16; ++r) {
                float dot = (a0[r] + a1[r]) + a2[r];
                float qd  = fmaf(-2.0f, dot, cnv);   // dist - vnorm (vn const per row)
                if (qd < bq[r]) { bq[r] = qd; bi[r] = n; }
            }
        }
    }

    // cross-lane argmin per row (reduce over the 32 cols; xor<=16 keeps h fixed)
    #pragma unroll
    for (int r = 0; r < 16; ++r) {
        float v = bq[r]; int i = bi[r];
        #pragma unroll
        for (int off = 16; off > 0; off >>= 1) {
            float ov = __shfl_xor(v, off);
            int   oi = __shfl_xor(i, off);
            if (ov < v || (ov == v && oi < i)) { v = ov; i = oi; }
        }
        bq[r] = v; bi[r] = i;
    }

    if (col == 0) {
        float esum = 0.0f;
        #pragma unroll
        for (int r = 0; r < 16; ++r) {
            int row = (r & 3) + 8 * (r >> 2) + 4 * h;   // C/D row mapping (m74/m101)
            int vid = wvec + row;
            float err = fmaxf(vnL[w][row] + bq[r], 0.0f);
            out[Z_OFF + vid] = (float)bi[r];
            out[E_OFF + vid] = err;
            zL[w][row] = bi[r];
            esum += err;
        }
        atomicAdd(out + LCOMMIT_OFF, esum * (1.0f / (float)NVEC));
    }

    // gather vecs_hat: 4 rows per iteration, fully coalesced 1KB stores
    #pragma unroll
    for (int it = 0; it < 8; ++it) {
        int row = it * 4 + (lane >> 4);
        int c4  = lane & 15;
        int z   = zL[w][row];
        float4 val = *(const float4*)(c32 + (size_t)z * KDIM + c4 * 4);
        *(float4*)(out + (size_t)(wvec + row) * KDIM + c4 * 4) = val;
    }
}

extern "C" void kernel_launch(void* const* d_in, const int* in_sizes, int n_in,
                              void* d_out, int out_size, void* d_ws, size_t ws_size,
                              hipStream_t stream) {
    const float* vecs    = (const float*)d_in[0];  // [8,16,512,64]
    const float* c_sum   = (const float*)d_in[1];  // [512,64]
    const float* c_count = (const float*)d_in[2];  // [512]
    float* out = (float*)d_out;

    float*    c32   = (float*)d_ws;                      // 128 KB
    float*    cnorm = c32 + SDIM * KDIM;                 // 2 KB
    _Float16* cbf16 = (_Float16*)(cnorm + SDIM);         // 128 KB

    vq_prep<<<SDIM, KDIM, 0, stream>>>(c_sum, c_count, c32, cnorm, cbf16, out);
    vq_main<<<NVEC / 64, 128, 0, stream>>>(vecs, cbf16, c32, cnorm, out);
}